// Round 1
// baseline (12454.549 us; speedup 1.0000x reference)
//
#include <hip/hip_runtime.h>
#include <hip/hip_bf16.h>

#define S_LEN 4096
#define NTAG 24
#define START_TAG 22
#define STOP_TAG 23

// ---------------- ws layout (bytes) ----------------
static const size_t OFF_WT    = 0;                               // [300][2048] f32 (w_ih_f|w_ih_b transposed)
static const size_t OFF_WHT   = OFF_WT + (size_t)300*2048*4;     // [2][256][1024] f32 (w_hh transposed)
static const size_t OFF_XG    = OFF_WHT + (size_t)2*256*1024*4;  // [2][4096][1024] f32 (x@W_ih^T + b)
static const size_t OFF_HS    = OFF_XG + (size_t)2*4096*1024*4;  // [2][4096][256] f32 (hidden states)
static const size_t OFF_FEATS = OFF_HS + (size_t)2*4096*256*4;   // [4096][24] f32
static const size_t OFF_BP    = OFF_FEATS + (size_t)4096*24*4;   // [4096][24] u8 backpointers
static const size_t OFF_FLAGS = OFF_BP + (size_t)4096*24;        // [2][8][16] int flags

__device__ __forceinline__ float sigf(float x) {
    return __fdividef(1.f, 1.f + __expf(-x));
}
__device__ __forceinline__ float tanhfast(float x) {
    return 1.f - __fdividef(2.f, 1.f + __expf(2.f * x));
}

// ---------------- prep: transpose weights, zero flags ----------------
__global__ void prep_kernel(const float* __restrict__ w_ih_f, const float* __restrict__ w_ih_b,
                            const float* __restrict__ w_hh_f, const float* __restrict__ w_hh_b,
                            float* __restrict__ WT, float* __restrict__ WHT, int* __restrict__ flags) {
    int tid = blockIdx.x * blockDim.x + threadIdx.x;
    int nth = gridDim.x * blockDim.x;
    // WT[k][col]: col<1024 -> w_ih_f[col][k], else w_ih_b[col-1024][k]
    for (int idx = tid; idx < 300 * 2048; idx += nth) {
        int k = idx / 2048, col = idx % 2048;
        WT[idx] = (col < 1024) ? w_ih_f[col * 300 + k] : w_ih_b[(col - 1024) * 300 + k];
    }
    // WHT[d][k][row]
    for (int idx = tid; idx < 2 * 256 * 1024; idx += nth) {
        int d = idx / (256 * 1024);
        int rem = idx - d * (256 * 1024);
        int k = rem / 1024, row = rem % 1024;
        const float* w = d ? w_hh_b : w_hh_f;
        WHT[idx] = w[row * 256 + k];
    }
    if (blockIdx.x == 0 && threadIdx.x < 256) flags[threadIdx.x] = 0;
}

// ---------------- embed + input projection ----------------
__global__ __launch_bounds__(256) void embed_xg_kernel(const int* __restrict__ sentence,
                                                       const float* __restrict__ emb,
                                                       const float* __restrict__ WT,
                                                       const float* __restrict__ b_f,
                                                       const float* __restrict__ b_b,
                                                       float* __restrict__ xg) {
    __shared__ float xs[16][300];
    int s0 = blockIdx.x * 16;
    for (int idx = threadIdx.x; idx < 16 * 300; idx += 256) {
        int si = idx / 300, k = idx - si * 300;
        int wrow = sentence[s0 + si];
        xs[si][k] = emb[(size_t)wrow * 300 + k];
    }
    __syncthreads();
    for (int chunk = 0; chunk < 8; ++chunk) {
        int col = chunk * 256 + threadIdx.x;   // 0..2047
        float acc[16];
#pragma unroll
        for (int s = 0; s < 16; ++s) acc[s] = 0.f;
        for (int k = 0; k < 300; k += 4) {
            float w0 = WT[(k + 0) * 2048 + col];
            float w1 = WT[(k + 1) * 2048 + col];
            float w2 = WT[(k + 2) * 2048 + col];
            float w3 = WT[(k + 3) * 2048 + col];
#pragma unroll
            for (int s = 0; s < 16; ++s) {
                float4 x4 = *reinterpret_cast<const float4*>(&xs[s][k]);
                acc[s] += w0 * x4.x + w1 * x4.y + w2 * x4.z + w3 * x4.w;
            }
        }
        int dir = col >> 10;
        int row = col & 1023;
        float bias = dir ? b_b[row] : b_f[row];
#pragma unroll
        for (int s = 0; s < 16; ++s)
            xg[((size_t)dir * S_LEN + (s0 + s)) * 1024 + row] = acc[s] + bias;
    }
}

// ---------------- recurrent LSTM: 8 blocks/dir, spin-sync h broadcast ----------------
__global__ __launch_bounds__(1024) void lstm_kernel(const float* __restrict__ xg,
                                                    const float* __restrict__ WHT,
                                                    float* __restrict__ hs,
                                                    int* __restrict__ flags) {
    const int dir = blockIdx.x >> 3;
    const int blk = blockIdx.x & 7;
    const int tid = threadIdx.x;
    const int rq = tid >> 5;   // 0..31 : row-quad (4 local rows)
    const int kc = tid & 31;   // 0..31 : k-slice (8 strided k elems)

    __shared__ float hprev[256];
    __shared__ float part[128][33];
    __shared__ float gl[4][32];

    const float* whtd = WHT + (size_t)dir * 256 * 1024;
    // thread owns local rows lr = rq*4+j ; k elems k = kc + 32*m (strided: LDS-conflict-free)
    float w[32];
#pragma unroll
    for (int j = 0; j < 4; ++j) {
        int lr = rq * 4 + j;
        int grow = ((lr >> 5) << 8) + blk * 32 + (lr & 31);
#pragma unroll
        for (int m = 0; m < 8; ++m)
            w[j * 8 + m] = whtd[(kc + 32 * m) * 1024 + grow];
    }
    int grow_r = 0;
    if (tid < 128) grow_r = ((tid >> 5) << 8) + blk * 32 + (tid & 31);

    if (tid < 256) hprev[tid] = 0.f;
    const float* xgd = xg + (size_t)dir * S_LEN * 1024;
    float* hsd = hs + (size_t)dir * S_LEN * 256;
    int* flg = flags + dir * 8 * 16;
    float c = 0.f;
    float xg_cur = (tid < 128) ? xgd[(size_t)(dir ? (S_LEN - 1) : 0) * 1024 + grow_r] : 0.f;
    __syncthreads();

    for (int step = 0; step < S_LEN; ++step) {
        const int st = dir ? (S_LEN - 1 - step) : step;
        // prefetch next step's xg
        float xg_nxt = 0.f;
        if (tid < 128 && step < S_LEN - 1) {
            const int stn = dir ? (st - 1) : (st + 1);
            xg_nxt = xgd[(size_t)stn * 1024 + grow_r];
        }
        // partial dot: 8 strided h elems x 4 rows
        float hv[8];
#pragma unroll
        for (int m = 0; m < 8; ++m) hv[m] = hprev[kc + 32 * m];
#pragma unroll
        for (int j = 0; j < 4; ++j) {
            float a = w[j * 8 + 0] * hv[0] + w[j * 8 + 1] * hv[1] + w[j * 8 + 2] * hv[2] + w[j * 8 + 3] * hv[3]
                    + w[j * 8 + 4] * hv[4] + w[j * 8 + 5] * hv[5] + w[j * 8 + 6] * hv[6] + w[j * 8 + 7] * hv[7];
            part[rq * 4 + j][kc] = a;
        }
        __syncthreads();                                   // B1
        if (tid < 128) {
            float g = xg_cur;
#pragma unroll
            for (int k2 = 0; k2 < 32; ++k2) g += part[tid][k2];
            gl[tid >> 5][tid & 31] = g;
        }
        __syncthreads();                                   // B2
        // wave 0 does gate math, h store, flag post (program order within wave)
        if (tid < 32) {
            float gi = gl[0][tid], gf = gl[1][tid], gg = gl[2][tid], go = gl[3][tid];
            float si = sigf(gi), sf = sigf(gf), so = sigf(go);
            c = sf * c + si * tanhfast(gg);
            float h = so * tanhfast(c);
            hsd[(size_t)st * 256 + blk * 32 + tid] = h;
            __threadfence();
        }
        if (tid == 0)
            __hip_atomic_store(&flg[blk * 16], step + 1, __ATOMIC_RELEASE, __HIP_MEMORY_SCOPE_AGENT);
        if (tid < 8) {
            while (__hip_atomic_load(&flg[tid * 16], __ATOMIC_ACQUIRE, __HIP_MEMORY_SCOPE_AGENT) <= step)
                __builtin_amdgcn_s_sleep(1);
        }
        __syncthreads();                                   // B4
        if (tid < 256)
            hprev[tid] = __hip_atomic_load(&hsd[(size_t)st * 256 + tid], __ATOMIC_RELAXED, __HIP_MEMORY_SCOPE_AGENT);
        xg_cur = xg_nxt;
        __syncthreads();                                   // B5
    }
}

// ---------------- feats = h @ w_tag^T + b_tag ----------------
__global__ __launch_bounds__(384) void feats_kernel(const float* __restrict__ hs,
                                                    const float* __restrict__ w_tag,
                                                    const float* __restrict__ b_tag,
                                                    float* __restrict__ feats) {
    __shared__ float ht[16][512];
    int s0 = blockIdx.x * 16;
    for (int idx = threadIdx.x; idx < 16 * 512; idx += 384) {
        int si = idx >> 9, k = idx & 511;
        float v = (k < 256) ? hs[(size_t)(s0 + si) * 256 + k]
                            : hs[(size_t)S_LEN * 256 + (size_t)(s0 + si) * 256 + (k - 256)];
        ht[si][k] = v;
    }
    __syncthreads();
    int si = threadIdx.x / NTAG;
    int t = threadIdx.x - si * NTAG;
    float acc = b_tag[t];
    const float* wr = w_tag + t * 512;
    for (int k = 0; k < 512; k += 4) {
        float4 w4 = *reinterpret_cast<const float4*>(&wr[k]);
        float4 h4 = *reinterpret_cast<const float4*>(&ht[si][k]);
        acc += w4.x * h4.x + w4.y * h4.y + w4.z * h4.z + w4.w * h4.w;
    }
    feats[(size_t)(s0 + si) * NTAG + t] = acc;
}

// ---------------- Viterbi (single wave) + backtrack ----------------
__global__ __launch_bounds__(64) void viterbi_kernel(const float* __restrict__ feats,
                                                     const float* __restrict__ trans,
                                                     unsigned char* __restrict__ bp_g,
                                                     float* __restrict__ out) {
    const int lane = threadIdx.x;
    const bool act = lane < NTAG;
    float wt[NTAG];
#pragma unroll
    for (int f = 0; f < NTAG; ++f) wt[f] = act ? trans[lane * NTAG + f] : -3.0e38f;
    float v = act ? ((lane == START_TAG) ? 0.f : -10000.f) : -3.0e38f;
    float feat = act ? feats[lane] : 0.f;

    for (int s = 0; s < S_LEN; ++s) {
        float featn = (act && s + 1 < S_LEN) ? feats[(s + 1) * NTAG + lane] : 0.f;
        float cand[NTAG];
#pragma unroll
        for (int f = 0; f < NTAG; ++f) cand[f] = __shfl(v, f) + wt[f];
        // max via tree
        float red[12];
#pragma unroll
        for (int i = 0; i < 12; ++i) red[i] = fmaxf(cand[i], cand[i + 12]);
#pragma unroll
        for (int i = 0; i < 6; ++i) red[i] = fmaxf(red[i], red[i + 6]);
#pragma unroll
        for (int i = 0; i < 3; ++i) red[i] = fmaxf(red[i], red[i + 3]);
        float m = fmaxf(fmaxf(red[0], red[1]), red[2]);
        // first index achieving max (matches jnp.argmax tie rule)
        int bi = 0;
#pragma unroll
        for (int f = NTAG - 1; f >= 0; --f)
            if (cand[f] == m) bi = f;
        v = m + feat;
        if (act) bp_g[s * NTAG + lane] = (unsigned char)bi;
        feat = featn;
    }

    // termination
    float wstop = act ? trans[STOP_TAG * NTAG + lane] : 0.f;
    float term = act ? (v + wstop) : -3.0e38f;
    float bv = term;
    int bti = lane;
#pragma unroll
    for (int d = 1; d < 64; d <<= 1) {
        float ov = __shfl_xor(bv, d);
        int oi = __shfl_xor(bti, d);
        if (ov > bv || (ov == bv && oi < bti)) { bv = ov; bti = oi; }
    }
    __threadfence_block();
    __syncthreads();

    // chunked backtrack: stage 2048 steps of bp into LDS at a time
    __shared__ unsigned char bpl[2048 * NTAG];  // 48 KB
    int tag = bti;
    for (int ch = 1; ch >= 0; --ch) {
        const uint4* src = (const uint4*)(bp_g + (size_t)ch * 2048 * NTAG);
        uint4* dst = (uint4*)bpl;
        for (int i = lane; i < 2048 * NTAG / 16; i += 64) dst[i] = src[i];
        __syncthreads();
        if (lane == 0) {
            for (int s = 2047; s >= 0; --s) {
                out[1 + ch * 2048 + s] = (float)tag;
                tag = bpl[s * NTAG + tag];
            }
        }
        __syncthreads();
        tag = __shfl(tag, 0);  // keep uniform for next chunk (lane0 authoritative)
    }
    if (lane == 0) out[0] = bv;
}

// ---------------- launch ----------------
extern "C" void kernel_launch(void* const* d_in, const int* in_sizes, int n_in,
                              void* d_out, int out_size, void* d_ws, size_t ws_size,
                              hipStream_t stream) {
    const int*   sentence = (const int*)d_in[0];
    const float* emb      = (const float*)d_in[1];
    const float* w_ih_f   = (const float*)d_in[2];
    const float* w_hh_f   = (const float*)d_in[3];
    const float* b_f      = (const float*)d_in[4];
    const float* w_ih_b   = (const float*)d_in[5];
    const float* w_hh_b   = (const float*)d_in[6];
    const float* b_b      = (const float*)d_in[7];
    const float* w_tag    = (const float*)d_in[8];
    const float* b_tag    = (const float*)d_in[9];
    const float* trans    = (const float*)d_in[10];

    char* ws = (char*)d_ws;
    float*         WT    = (float*)(ws + OFF_WT);
    float*         WHT   = (float*)(ws + OFF_WHT);
    float*         XG    = (float*)(ws + OFF_XG);
    float*         HS    = (float*)(ws + OFF_HS);
    float*         FEATS = (float*)(ws + OFF_FEATS);
    unsigned char* BP    = (unsigned char*)(ws + OFF_BP);
    int*           FLAGS = (int*)(ws + OFF_FLAGS);

    float* out = (float*)d_out;

    prep_kernel<<<512, 256, 0, stream>>>(w_ih_f, w_ih_b, w_hh_f, w_hh_b, WT, WHT, FLAGS);
    embed_xg_kernel<<<S_LEN / 16, 256, 0, stream>>>(sentence, emb, WT, b_f, b_b, XG);
    lstm_kernel<<<16, 1024, 0, stream>>>(XG, WHT, HS, FLAGS);
    feats_kernel<<<S_LEN / 16, 384, 0, stream>>>(HS, w_tag, b_tag, FEATS);
    viterbi_kernel<<<1, 64, 0, stream>>>(FEATS, trans, BP, out);
}

// Round 2
// 8464.403 us; speedup vs baseline: 1.4714x; 1.4714x over previous
//
#include <hip/hip_runtime.h>
#include <hip/hip_bf16.h>

#define S_LEN 4096
#define NTAG 24
#define START_TAG 22
#define STOP_TAG 23
#define SENT 0x7F800001u

// ---------------- ws layout (bytes) ----------------
static const size_t OFF_WT    = 0;                               // [300][2048] f32 (w_ih_f|w_ih_b transposed)
static const size_t OFF_XG    = OFF_WT + (size_t)300*2048*4;     // [2][4096][1024] f32 (x@W_ih^T + b)
static const size_t OFF_HS    = OFF_XG + (size_t)2*4096*1024*4;  // [2][4096][256] f32 (hidden states)
static const size_t OFF_FEATS = OFF_HS + (size_t)2*4096*256*4;   // [4096][24] f32
static const size_t OFF_BP    = OFF_FEATS + (size_t)4096*24*4;   // [4096][24] u8 backpointers

__device__ __forceinline__ float sigf(float x) {
    return __fdividef(1.f, 1.f + __expf(-x));
}
__device__ __forceinline__ float tanhfast(float x) {
    return 1.f - __fdividef(2.f, 1.f + __expf(2.f * x));
}

// ---------------- prep: transpose W_ih, sentinel-fill HS ----------------
__global__ void prep_kernel(const float* __restrict__ w_ih_f, const float* __restrict__ w_ih_b,
                            float* __restrict__ WT, unsigned int* __restrict__ HSu) {
    int tid = blockIdx.x * blockDim.x + threadIdx.x;
    int nth = gridDim.x * blockDim.x;
    // WT[k][col]: col<1024 -> w_ih_f[col][k], else w_ih_b[col-1024][k]
    for (int idx = tid; idx < 300 * 2048; idx += nth) {
        int k = idx / 2048, col = idx % 2048;
        WT[idx] = (col < 1024) ? w_ih_f[col * 300 + k] : w_ih_b[(col - 1024) * 300 + k];
    }
    // sentinel-fill hidden-state buffer (2*4096*256 words) — every launch (graph-replay safe)
    for (int idx = tid; idx < 2 * S_LEN * 256; idx += nth)
        HSu[idx] = SENT;
}

// ---------------- embed + input projection ----------------
__global__ __launch_bounds__(256) void embed_xg_kernel(const int* __restrict__ sentence,
                                                       const float* __restrict__ emb,
                                                       const float* __restrict__ WT,
                                                       const float* __restrict__ b_f,
                                                       const float* __restrict__ b_b,
                                                       float* __restrict__ xg) {
    __shared__ float xs[16][300];
    int s0 = blockIdx.x * 16;
    for (int idx = threadIdx.x; idx < 16 * 300; idx += 256) {
        int si = idx / 300, k = idx - si * 300;
        int wrow = sentence[s0 + si];
        xs[si][k] = emb[(size_t)wrow * 300 + k];
    }
    __syncthreads();
    for (int chunk = 0; chunk < 8; ++chunk) {
        int col = chunk * 256 + threadIdx.x;   // 0..2047
        float acc[16];
#pragma unroll
        for (int s = 0; s < 16; ++s) acc[s] = 0.f;
        for (int k = 0; k < 300; k += 4) {
            float w0 = WT[(k + 0) * 2048 + col];
            float w1 = WT[(k + 1) * 2048 + col];
            float w2 = WT[(k + 2) * 2048 + col];
            float w3 = WT[(k + 3) * 2048 + col];
#pragma unroll
            for (int s = 0; s < 16; ++s) {
                float4 x4 = *reinterpret_cast<const float4*>(&xs[s][k]);
                acc[s] += w0 * x4.x + w1 * x4.y + w2 * x4.z + w3 * x4.w;
            }
        }
        int dir = col >> 10;
        int row = col & 1023;
        float bias = dir ? b_b[row] : b_f[row];
#pragma unroll
        for (int s = 0; s < 16; ++s)
            xg[((size_t)dir * S_LEN + (s0 + s)) * 1024 + row] = acc[s] + bias;
    }
}

// ---------------- recurrent LSTM: 8 blocks/dir, 1-hop sentinel-poll h exchange ----------------
// thread = (r4 = tid>>5 in 0..31 : 4 gate-rows, kc = tid&31 : 8 contiguous k at kc*8)
__global__ __launch_bounds__(1024) void lstm_kernel(const float* __restrict__ xg,
                                                    const float* __restrict__ w_hh_f,
                                                    const float* __restrict__ w_hh_b,
                                                    float* __restrict__ hs) {
    const int dir = blockIdx.x >> 3;
    const int blk = blockIdx.x & 7;
    const int tid = threadIdx.x;
    const int r4 = tid >> 5;
    const int kc = tid & 31;

    __shared__ float hsk[32 * 10];     // skewed h_prev: word w -> hsk[(w>>3)*10 + (w&7)]
    __shared__ float part[128][33];    // partial sums [gate-row][k-chunk]
    __shared__ float gl[128];          // reduced gates

    const float* whh = dir ? w_hh_b : w_hh_f;   // [1024][256], row = g*256 + h_out
    // weights: rows R = r4*4+q (local: g = R>>5, hr = R&31 -> global row g*256 + blk*32 + hr)
    float w[4][8];
#pragma unroll
    for (int q = 0; q < 4; ++q) {
        int R = r4 * 4 + q;
        int grow = ((R >> 5) << 8) + blk * 32 + (R & 31);
#pragma unroll
        for (int j = 0; j < 8; ++j)
            w[q][j] = whh[(size_t)grow * 256 + kc * 8 + j];
    }

    for (int i = tid; i < 320; i += 1024) hsk[i] = 0.f;   // h(-1) = 0

    const float* xgd = xg + (size_t)dir * S_LEN * 1024;
    float* hsd = hs + (size_t)dir * S_LEN * 256;
    float c = 0.f;
    int growR = 0;
    float xg_cur = 0.f;
    if (tid < 128) {
        growR = ((tid >> 5) << 8) + blk * 32 + (tid & 31);
        xg_cur = xgd[(size_t)(dir ? (S_LEN - 1) : 0) * 1024 + growR];
    }
    __syncthreads();

    for (int step = 0; step < S_LEN; ++step) {
        const int st = dir ? (S_LEN - 1 - step) : step;

        // ---- dot: 4 rows x 8 k per thread ----
        float hv[8];
        const int hb = kc * 10;
#pragma unroll
        for (int j = 0; j < 8; ++j) hv[j] = hsk[hb + j];
        float p0 = 0.f, p1 = 0.f, p2 = 0.f, p3 = 0.f;
#pragma unroll
        for (int j = 0; j < 8; ++j) {
            p0 += w[0][j] * hv[j];
            p1 += w[1][j] * hv[j];
            p2 += w[2][j] * hv[j];
            p3 += w[3][j] * hv[j];
        }
        part[r4 * 4 + 0][kc] = p0;
        part[r4 * 4 + 1][kc] = p1;
        part[r4 * 4 + 2][kc] = p2;
        part[r4 * 4 + 3][kc] = p3;
        __syncthreads();                                   // B1

        // ---- reduce 32 partials + xg ----
        float xg_nxt = 0.f;
        if (tid < 128) {
            if (step + 1 < S_LEN) {
                const int stn = dir ? (st - 1) : (st + 1);
                xg_nxt = xgd[(size_t)stn * 1024 + growR];  // prefetch, used next iter
            }
            float a0 = 0.f, a1 = 0.f, a2 = 0.f, a3 = 0.f;
#pragma unroll
            for (int k2 = 0; k2 < 32; k2 += 4) {
                a0 += part[tid][k2 + 0];
                a1 += part[tid][k2 + 1];
                a2 += part[tid][k2 + 2];
                a3 += part[tid][k2 + 3];
            }
            gl[tid] = xg_cur + ((a0 + a1) + (a2 + a3));
        }
        __syncthreads();                                   // B2

        // ---- gates + h store (wave 0, lanes 0..31 : h rows blk*32+lane) ----
        if (tid < 32) {
            float gi = gl[tid], gf = gl[32 + tid], gg = gl[64 + tid], go = gl[96 + tid];
            float si = sigf(gi), sf = sigf(gf), so = sigf(go);
            c = sf * c + si * tanhfast(gg);
            float h = so * tanhfast(c);
            __hip_atomic_store(&hsd[(size_t)st * 256 + blk * 32 + tid], h,
                               __ATOMIC_RELAXED, __HIP_MEMORY_SCOPE_AGENT);
            int w0 = blk * 32 + tid;
            hsk[(w0 >> 3) * 10 + (w0 & 7)] = h;            // own slice -> LDS directly
        }
        // ---- poll remote h words (1 word/thread, sentinel-validated) ----
        if (tid < 256 && (tid >> 5) != blk && step + 1 < S_LEN) {
            const float* src = &hsd[(size_t)st * 256 + tid];
            float v;
            do {
                v = __hip_atomic_load(src, __ATOMIC_RELAXED, __HIP_MEMORY_SCOPE_AGENT);
            } while (__float_as_uint(v) == SENT);
            hsk[(tid >> 3) * 10 + (tid & 7)] = v;
        }
        xg_cur = xg_nxt;
        __syncthreads();                                   // B3
    }
}

// ---------------- feats = h @ w_tag^T + b_tag ----------------
__global__ __launch_bounds__(384) void feats_kernel(const float* __restrict__ hs,
                                                    const float* __restrict__ w_tag,
                                                    const float* __restrict__ b_tag,
                                                    float* __restrict__ feats) {
    __shared__ float ht[16][512];
    int s0 = blockIdx.x * 16;
    for (int idx = threadIdx.x; idx < 16 * 512; idx += 384) {
        int si = idx >> 9, k = idx & 511;
        float v = (k < 256) ? hs[(size_t)(s0 + si) * 256 + k]
                            : hs[(size_t)S_LEN * 256 + (size_t)(s0 + si) * 256 + (k - 256)];
        ht[si][k] = v;
    }
    __syncthreads();
    int si = threadIdx.x / NTAG;
    int t = threadIdx.x - si * NTAG;
    float acc = b_tag[t];
    const float* wr = w_tag + t * 512;
    for (int k = 0; k < 512; k += 4) {
        float4 w4 = *reinterpret_cast<const float4*>(&wr[k]);
        float4 h4 = *reinterpret_cast<const float4*>(&ht[si][k]);
        acc += w4.x * h4.x + w4.y * h4.y + w4.z * h4.z + w4.w * h4.w;
    }
    feats[(size_t)(s0 + si) * NTAG + t] = acc;
}

// ---------------- Viterbi (single wave) + backtrack ----------------
__global__ __launch_bounds__(64) void viterbi_kernel(const float* __restrict__ feats,
                                                     const float* __restrict__ trans,
                                                     unsigned char* __restrict__ bp_g,
                                                     float* __restrict__ out) {
    const int lane = threadIdx.x;
    const bool act = lane < NTAG;
    float wt[NTAG];
#pragma unroll
    for (int f = 0; f < NTAG; ++f) wt[f] = act ? trans[lane * NTAG + f] : -3.0e38f;
    float v = act ? ((lane == START_TAG) ? 0.f : -10000.f) : -3.0e38f;
    float feat = act ? feats[lane] : 0.f;

    for (int s = 0; s < S_LEN; ++s) {
        float featn = (act && s + 1 < S_LEN) ? feats[(s + 1) * NTAG + lane] : 0.f;
        float cand[NTAG];
#pragma unroll
        for (int f = 0; f < NTAG; ++f) cand[f] = __shfl(v, f) + wt[f];
        float red[12];
#pragma unroll
        for (int i = 0; i < 12; ++i) red[i] = fmaxf(cand[i], cand[i + 12]);
#pragma unroll
        for (int i = 0; i < 6; ++i) red[i] = fmaxf(red[i], red[i + 6]);
#pragma unroll
        for (int i = 0; i < 3; ++i) red[i] = fmaxf(red[i], red[i + 3]);
        float m = fmaxf(fmaxf(red[0], red[1]), red[2]);
        int bi = 0;
#pragma unroll
        for (int f = NTAG - 1; f >= 0; --f)
            if (cand[f] == m) bi = f;
        v = m + feat;
        if (act) bp_g[s * NTAG + lane] = (unsigned char)bi;
        feat = featn;
    }

    float wstop = act ? trans[STOP_TAG * NTAG + lane] : 0.f;
    float term = act ? (v + wstop) : -3.0e38f;
    float bv = term;
    int bti = lane;
#pragma unroll
    for (int d = 1; d < 64; d <<= 1) {
        float ov = __shfl_xor(bv, d);
        int oi = __shfl_xor(bti, d);
        if (ov > bv || (ov == bv && oi < bti)) { bv = ov; bti = oi; }
    }
    __threadfence_block();
    __syncthreads();

    __shared__ unsigned char bpl[2048 * NTAG];  // 48 KB
    int tag = bti;
    for (int ch = 1; ch >= 0; --ch) {
        const uint4* src = (const uint4*)(bp_g + (size_t)ch * 2048 * NTAG);
        uint4* dst = (uint4*)bpl;
        for (int i = lane; i < 2048 * NTAG / 16; i += 64) dst[i] = src[i];
        __syncthreads();
        if (lane == 0) {
            for (int s = 2047; s >= 0; --s) {
                out[1 + ch * 2048 + s] = (float)tag;
                tag = bpl[s * NTAG + tag];
            }
        }
        __syncthreads();
        tag = __shfl(tag, 0);
    }
    if (lane == 0) out[0] = bv;
}

// ---------------- launch ----------------
extern "C" void kernel_launch(void* const* d_in, const int* in_sizes, int n_in,
                              void* d_out, int out_size, void* d_ws, size_t ws_size,
                              hipStream_t stream) {
    const int*   sentence = (const int*)d_in[0];
    const float* emb      = (const float*)d_in[1];
    const float* w_ih_f   = (const float*)d_in[2];
    const float* w_hh_f   = (const float*)d_in[3];
    const float* b_f      = (const float*)d_in[4];
    const float* w_ih_b   = (const float*)d_in[5];
    const float* w_hh_b   = (const float*)d_in[6];
    const float* b_b      = (const float*)d_in[7];
    const float* w_tag    = (const float*)d_in[8];
    const float* b_tag    = (const float*)d_in[9];
    const float* trans    = (const float*)d_in[10];

    char* ws = (char*)d_ws;
    float*         WT    = (float*)(ws + OFF_WT);
    float*         XG    = (float*)(ws + OFF_XG);
    float*         HS    = (float*)(ws + OFF_HS);
    float*         FEATS = (float*)(ws + OFF_FEATS);
    unsigned char* BP    = (unsigned char*)(ws + OFF_BP);

    float* out = (float*)d_out;

    prep_kernel<<<512, 256, 0, stream>>>(w_ih_f, w_ih_b, WT, (unsigned int*)HS);
    embed_xg_kernel<<<S_LEN / 16, 256, 0, stream>>>(sentence, emb, WT, b_f, b_b, XG);
    lstm_kernel<<<16, 1024, 0, stream>>>(XG, w_hh_f, w_hh_b, HS);
    feats_kernel<<<S_LEN / 16, 384, 0, stream>>>(HS, w_tag, b_tag, FEATS);
    viterbi_kernel<<<1, 64, 0, stream>>>(FEATS, trans, BP, out);
}

// Round 3
// 7707.584 us; speedup vs baseline: 1.6159x; 1.0982x over previous
//
#include <hip/hip_runtime.h>
#include <hip/hip_bf16.h>

#define S_LEN 4096
#define NTAG 24
#define START_TAG 22
#define STOP_TAG 23
#define SENT 0x7F800001u

// ---------------- ws layout (bytes) ----------------
static const size_t OFF_WT    = 0;                               // [300][2048] f32 (w_ih_f|w_ih_b transposed)
static const size_t OFF_XG    = OFF_WT + (size_t)300*2048*4;     // [2][4096][1024] f32 (x@W_ih^T + b)
static const size_t OFF_HS    = OFF_XG + (size_t)2*4096*1024*4;  // [2][4096][256] f32 (hidden states)
static const size_t OFF_FEATS = OFF_HS + (size_t)2*4096*256*4;   // [4096][24] f32
static const size_t OFF_BP    = OFF_FEATS + (size_t)4096*24*4;   // [4096][24] u8 backpointers

__device__ __forceinline__ float sigf(float x) {
    return __fdividef(1.f, 1.f + __expf(-x));
}
__device__ __forceinline__ float tanhfast(float x) {
    return 1.f - __fdividef(2.f, 1.f + __expf(2.f * x));
}

// ---------------- prep: transpose W_ih, sentinel-fill HS ----------------
__global__ void prep_kernel(const float* __restrict__ w_ih_f, const float* __restrict__ w_ih_b,
                            float* __restrict__ WT, unsigned int* __restrict__ HSu) {
    int tid = blockIdx.x * blockDim.x + threadIdx.x;
    int nth = gridDim.x * blockDim.x;
    // WT[k][col]: col<1024 -> w_ih_f[col][k], else w_ih_b[col-1024][k]
    for (int idx = tid; idx < 300 * 2048; idx += nth) {
        int k = idx / 2048, col = idx % 2048;
        WT[idx] = (col < 1024) ? w_ih_f[col * 300 + k] : w_ih_b[(col - 1024) * 300 + k];
    }
    // sentinel-fill hidden-state buffer (2*4096*256 words) — every launch (graph-replay safe)
    for (int idx = tid; idx < 2 * S_LEN * 256; idx += nth)
        HSu[idx] = SENT;
}

// ---------------- embed + input projection ----------------
__global__ __launch_bounds__(256) void embed_xg_kernel(const int* __restrict__ sentence,
                                                       const float* __restrict__ emb,
                                                       const float* __restrict__ WT,
                                                       const float* __restrict__ b_f,
                                                       const float* __restrict__ b_b,
                                                       float* __restrict__ xg) {
    __shared__ float xs[16][300];
    int s0 = blockIdx.x * 16;
    for (int idx = threadIdx.x; idx < 16 * 300; idx += 256) {
        int si = idx / 300, k = idx - si * 300;
        int wrow = sentence[s0 + si];
        xs[si][k] = emb[(size_t)wrow * 300 + k];
    }
    __syncthreads();
    for (int chunk = 0; chunk < 8; ++chunk) {
        int col = chunk * 256 + threadIdx.x;   // 0..2047
        float acc[16];
#pragma unroll
        for (int s = 0; s < 16; ++s) acc[s] = 0.f;
        for (int k = 0; k < 300; k += 4) {
            float w0 = WT[(k + 0) * 2048 + col];
            float w1 = WT[(k + 1) * 2048 + col];
            float w2 = WT[(k + 2) * 2048 + col];
            float w3 = WT[(k + 3) * 2048 + col];
#pragma unroll
            for (int s = 0; s < 16; ++s) {
                float4 x4 = *reinterpret_cast<const float4*>(&xs[s][k]);
                acc[s] += w0 * x4.x + w1 * x4.y + w2 * x4.z + w3 * x4.w;
            }
        }
        int dir = col >> 10;
        int row = col & 1023;
        float bias = dir ? b_b[row] : b_f[row];
#pragma unroll
        for (int s = 0; s < 16; ++s)
            xg[((size_t)dir * S_LEN + (s0 + s)) * 1024 + row] = acc[s] + bias;
    }
}

// ---------------- recurrent LSTM: 8 blocks/dir pinned to ONE XCD via blockIdx%8 ----------------
// launch 64 blocks; only (id&7)<2 are active: dir = id&7, rank = id>>3.
// dir-0 ranks are blocks {0,8,...,56} -> all XCD 0; dir-1 -> all XCD 1 (dispatch round-robin).
// thread = (r4 = tid>>5 in 0..31 : 4 gate-rows, kc = tid&31 : 8 contiguous k at kc*8)
__global__ __launch_bounds__(1024) void lstm_kernel(const float* __restrict__ xg,
                                                    const float* __restrict__ w_hh_f,
                                                    const float* __restrict__ w_hh_b,
                                                    float* __restrict__ hs) {
    const int xslot = blockIdx.x & 7;
    if (xslot > 1) return;                 // 48 inert blocks exit
    const int dir = xslot;
    const int blk = blockIdx.x >> 3;       // 0..7, all on the same XCD per dir
    const int tid = threadIdx.x;
    const int r4 = tid >> 5;
    const int kc = tid & 31;

    __shared__ float hsk[32 * 10];     // skewed h_prev: word w -> hsk[(w>>3)*10 + (w&7)]
    __shared__ float part[128][33];    // partial sums [gate-row][k-chunk]
    __shared__ float gl[128];          // reduced gates

    const float* whh = dir ? w_hh_b : w_hh_f;   // [1024][256], row = g*256 + h_out
    // weights: rows R = r4*4+q (local: g = R>>5, hr = R&31 -> global row g*256 + blk*32 + hr)
    float w[4][8];
#pragma unroll
    for (int q = 0; q < 4; ++q) {
        int R = r4 * 4 + q;
        int grow = ((R >> 5) << 8) + blk * 32 + (R & 31);
#pragma unroll
        for (int j = 0; j < 8; ++j)
            w[q][j] = whh[(size_t)grow * 256 + kc * 8 + j];
    }

    for (int i = tid; i < 320; i += 1024) hsk[i] = 0.f;   // h(-1) = 0

    const float* xgd = xg + (size_t)dir * S_LEN * 1024;
    float* hsd = hs + (size_t)dir * S_LEN * 256;
    float c = 0.f;
    int growR = 0;
    float xg_cur = 0.f;
    if (tid < 128) {
        growR = ((tid >> 5) << 8) + blk * 32 + (tid & 31);
        xg_cur = xgd[(size_t)(dir ? (S_LEN - 1) : 0) * 1024 + growR];
    }
    __syncthreads();

    for (int step = 0; step < S_LEN; ++step) {
        const int st = dir ? (S_LEN - 1 - step) : step;

        // ---- dot: 4 rows x 8 k per thread ----
        float hv[8];
        const int hb = kc * 10;
#pragma unroll
        for (int j = 0; j < 8; ++j) hv[j] = hsk[hb + j];
        float p0 = 0.f, p1 = 0.f, p2 = 0.f, p3 = 0.f;
#pragma unroll
        for (int j = 0; j < 8; ++j) {
            p0 += w[0][j] * hv[j];
            p1 += w[1][j] * hv[j];
            p2 += w[2][j] * hv[j];
            p3 += w[3][j] * hv[j];
        }
        part[r4 * 4 + 0][kc] = p0;
        part[r4 * 4 + 1][kc] = p1;
        part[r4 * 4 + 2][kc] = p2;
        part[r4 * 4 + 3][kc] = p3;
        __syncthreads();                                   // B1

        // ---- reduce 32 partials + xg ----
        float xg_nxt = 0.f;
        if (tid < 128) {
            if (step + 1 < S_LEN) {
                const int stn = dir ? (st - 1) : (st + 1);
                xg_nxt = xgd[(size_t)stn * 1024 + growR];  // prefetch, used next iter
            }
            float a0 = 0.f, a1 = 0.f, a2 = 0.f, a3 = 0.f;
#pragma unroll
            for (int k2 = 0; k2 < 32; k2 += 4) {
                a0 += part[tid][k2 + 0];
                a1 += part[tid][k2 + 1];
                a2 += part[tid][k2 + 2];
                a3 += part[tid][k2 + 3];
            }
            gl[tid] = xg_cur + ((a0 + a1) + (a2 + a3));
        }
        __syncthreads();                                   // B2

        // ---- gates + h store (wave 0, lanes 0..31 : h rows blk*32+lane) ----
        if (tid < 32) {
            float gi = gl[tid], gf = gl[32 + tid], gg = gl[64 + tid], go = gl[96 + tid];
            float si = sigf(gi), sf = sigf(gf), so = sigf(go);
            c = sf * c + si * tanhfast(gg);
            float h = so * tanhfast(c);
            __hip_atomic_store(&hsd[(size_t)st * 256 + blk * 32 + tid], h,
                               __ATOMIC_RELAXED, __HIP_MEMORY_SCOPE_AGENT);
            int w0 = blk * 32 + tid;
            hsk[(w0 >> 3) * 10 + (w0 & 7)] = h;            // own slice -> LDS directly
        }
        // ---- poll remote h words (1 word/thread, sentinel-validated) ----
        if (tid < 256 && (tid >> 5) != blk && step + 1 < S_LEN) {
            const float* src = &hsd[(size_t)st * 256 + tid];
            float v;
            do {
                v = __hip_atomic_load(src, __ATOMIC_RELAXED, __HIP_MEMORY_SCOPE_AGENT);
            } while (__float_as_uint(v) == SENT);
            hsk[(tid >> 3) * 10 + (tid & 7)] = v;
        }
        xg_cur = xg_nxt;
        __syncthreads();                                   // B3
    }
}

// ---------------- feats = h @ w_tag^T + b_tag ----------------
__global__ __launch_bounds__(384) void feats_kernel(const float* __restrict__ hs,
                                                    const float* __restrict__ w_tag,
                                                    const float* __restrict__ b_tag,
                                                    float* __restrict__ feats) {
    __shared__ float ht[16][512];
    int s0 = blockIdx.x * 16;
    for (int idx = threadIdx.x; idx < 16 * 512; idx += 384) {
        int si = idx >> 9, k = idx & 511;
        float v = (k < 256) ? hs[(size_t)(s0 + si) * 256 + k]
                            : hs[(size_t)S_LEN * 256 + (size_t)(s0 + si) * 256 + (k - 256)];
        ht[si][k] = v;
    }
    __syncthreads();
    int si = threadIdx.x / NTAG;
    int t = threadIdx.x - si * NTAG;
    float acc = b_tag[t];
    const float* wr = w_tag + t * 512;
    for (int k = 0; k < 512; k += 4) {
        float4 w4 = *reinterpret_cast<const float4*>(&wr[k]);
        float4 h4 = *reinterpret_cast<const float4*>(&ht[si][k]);
        acc += w4.x * h4.x + w4.y * h4.y + w4.z * h4.z + w4.w * h4.w;
    }
    feats[(size_t)(s0 + si) * NTAG + t] = acc;
}

// ---------------- Viterbi (single wave) + backtrack ----------------
__global__ __launch_bounds__(64) void viterbi_kernel(const float* __restrict__ feats,
                                                     const float* __restrict__ trans,
                                                     unsigned char* __restrict__ bp_g,
                                                     float* __restrict__ out) {
    const int lane = threadIdx.x;
    const bool act = lane < NTAG;
    float wt[NTAG];
#pragma unroll
    for (int f = 0; f < NTAG; ++f) wt[f] = act ? trans[lane * NTAG + f] : -3.0e38f;
    float v = act ? ((lane == START_TAG) ? 0.f : -10000.f) : -3.0e38f;
    float feat = act ? feats[lane] : 0.f;

    for (int s = 0; s < S_LEN; ++s) {
        float featn = (act && s + 1 < S_LEN) ? feats[(s + 1) * NTAG + lane] : 0.f;
        float cand[NTAG];
#pragma unroll
        for (int f = 0; f < NTAG; ++f) cand[f] = __shfl(v, f) + wt[f];
        float red[12];
#pragma unroll
        for (int i = 0; i < 12; ++i) red[i] = fmaxf(cand[i], cand[i + 12]);
#pragma unroll
        for (int i = 0; i < 6; ++i) red[i] = fmaxf(red[i], red[i + 6]);
#pragma unroll
        for (int i = 0; i < 3; ++i) red[i] = fmaxf(red[i], red[i + 3]);
        float m = fmaxf(fmaxf(red[0], red[1]), red[2]);
        int bi = 0;
#pragma unroll
        for (int f = NTAG - 1; f >= 0; --f)
            if (cand[f] == m) bi = f;
        v = m + feat;
        if (act) bp_g[s * NTAG + lane] = (unsigned char)bi;
        feat = featn;
    }

    float wstop = act ? trans[STOP_TAG * NTAG + lane] : 0.f;
    float term = act ? (v + wstop) : -3.0e38f;
    float bv = term;
    int bti = lane;
#pragma unroll
    for (int d = 1; d < 64; d <<= 1) {
        float ov = __shfl_xor(bv, d);
        int oi = __shfl_xor(bti, d);
        if (ov > bv || (ov == bv && oi < bti)) { bv = ov; bti = oi; }
    }
    __threadfence_block();
    __syncthreads();

    __shared__ unsigned char bpl[2048 * NTAG];  // 48 KB
    int tag = bti;
    for (int ch = 1; ch >= 0; --ch) {
        const uint4* src = (const uint4*)(bp_g + (size_t)ch * 2048 * NTAG);
        uint4* dst = (uint4*)bpl;
        for (int i = lane; i < 2048 * NTAG / 16; i += 64) dst[i] = src[i];
        __syncthreads();
        if (lane == 0) {
            for (int s = 2047; s >= 0; --s) {
                out[1 + ch * 2048 + s] = (float)tag;
                tag = bpl[s * NTAG + tag];
            }
        }
        __syncthreads();
        tag = __shfl(tag, 0);
    }
    if (lane == 0) out[0] = bv;
}

// ---------------- launch ----------------
extern "C" void kernel_launch(void* const* d_in, const int* in_sizes, int n_in,
                              void* d_out, int out_size, void* d_ws, size_t ws_size,
                              hipStream_t stream) {
    const int*   sentence = (const int*)d_in[0];
    const float* emb      = (const float*)d_in[1];
    const float* w_ih_f   = (const float*)d_in[2];
    const float* w_hh_f   = (const float*)d_in[3];
    const float* b_f      = (const float*)d_in[4];
    const float* w_ih_b   = (const float*)d_in[5];
    const float* w_hh_b   = (const float*)d_in[6];
    const float* b_b      = (const float*)d_in[7];
    const float* w_tag    = (const float*)d_in[8];
    const float* b_tag    = (const float*)d_in[9];
    const float* trans    = (const float*)d_in[10];

    char* ws = (char*)d_ws;
    float*         WT    = (float*)(ws + OFF_WT);
    float*         XG    = (float*)(ws + OFF_XG);
    float*         HS    = (float*)(ws + OFF_HS);
    float*         FEATS = (float*)(ws + OFF_FEATS);
    unsigned char* BP    = (unsigned char*)(ws + OFF_BP);

    float* out = (float*)d_out;

    prep_kernel<<<512, 256, 0, stream>>>(w_ih_f, w_ih_b, WT, (unsigned int*)HS);
    embed_xg_kernel<<<S_LEN / 16, 256, 0, stream>>>(sentence, emb, WT, b_f, b_b, XG);
    lstm_kernel<<<64, 1024, 0, stream>>>(XG, w_hh_f, w_hh_b, HS);
    feats_kernel<<<S_LEN / 16, 384, 0, stream>>>(HS, w_tag, b_tag, FEATS);
    viterbi_kernel<<<1, 64, 0, stream>>>(FEATS, trans, BP, out);
}